// Round 3
// baseline (1090.542 us; speedup 1.0000x reference)
//
#include <hip/hip_runtime.h>
#include <stdint.h>

typedef signed char i8;
typedef __attribute__((ext_vector_type(4))) float f32x4;
typedef __attribute__((ext_vector_type(4))) int i32x4;

#define XSCALE 32.0f
#define INV_XSCALE (1.0f / 32.0f)

// ---------------- conversion kernels ----------------

__device__ __forceinline__ int q8(float f) {
  float s = rintf(f * XSCALE);
  s = fminf(fmaxf(s, -127.0f), 127.0f);
  return ((int)s) & 0xff;
}

// x fp32 -> i8 (scale 32), 16 elems/thread
__global__ __launch_bounds__(256) void cvt_x_kernel(const float* __restrict__ x,
                                                    i32x4* __restrict__ o, int n16) {
  int i = blockIdx.x * blockDim.x + threadIdx.x;
  int stride = gridDim.x * blockDim.x;
  for (; i < n16; i += stride) {
    const f32x4* p = (const f32x4*)x + (size_t)i * 4;
    f32x4 v0 = p[0], v1 = p[1], v2 = p[2], v3 = p[3];
    i32x4 r;
    r[0] = q8(v0[0]) | (q8(v0[1]) << 8) | (q8(v0[2]) << 16) | (q8(v0[3]) << 24);
    r[1] = q8(v1[0]) | (q8(v1[1]) << 8) | (q8(v1[2]) << 16) | (q8(v1[3]) << 24);
    r[2] = q8(v2[0]) | (q8(v2[1]) << 8) | (q8(v2[2]) << 16) | (q8(v2[3]) << 24);
    r[3] = q8(v3[0]) | (q8(v3[1]) << 8) | (q8(v3[2]) << 16) | (q8(v3[3]) << 24);
    o[i] = r;
  }
}

__device__ __forceinline__ int sg8(float f) {
  return (f > 0.0f ? 1 : (f < 0.0f ? -1 : 0)) & 0xff;
}

// w fp32 -> sign i8 (+1/-1/0), 16 elems/thread
__global__ __launch_bounds__(256) void cvt_w_kernel(const float* __restrict__ w,
                                                    i32x4* __restrict__ o, int n16) {
  int i = blockIdx.x * blockDim.x + threadIdx.x;
  int stride = gridDim.x * blockDim.x;
  for (; i < n16; i += stride) {
    const f32x4* p = (const f32x4*)w + (size_t)i * 4;
    f32x4 v0 = p[0], v1 = p[1], v2 = p[2], v3 = p[3];
    i32x4 r;
    r[0] = sg8(v0[0]) | (sg8(v0[1]) << 8) | (sg8(v0[2]) << 16) | (sg8(v0[3]) << 24);
    r[1] = sg8(v1[0]) | (sg8(v1[1]) << 8) | (sg8(v1[2]) << 16) | (sg8(v1[3]) << 24);
    r[2] = sg8(v2[0]) | (sg8(v2[1]) << 8) | (sg8(v2[2]) << 16) | (sg8(v2[3]) << 24);
    r[3] = sg8(v3[0]) | (sg8(v3[1]) << 8) | (sg8(v3[2]) << 16) | (sg8(v3[3]) << 24);
    o[i] = r;
  }
}

// ---------------- 256x256 i8 MFMA GEMM, wait-free MFMA pipeline ------------
// r16: break the same-tile read->MFMA RAW. r12-r15 all measured the SUM
// signature (tile ~3150cyc = 1536 LDS + 1306 MFMA): every wave, in every
// occupancy config, reads tile t's frags then MFMAs tile t -- LDS and
// matrix pipes strictly alternate CU-wide (all waves share one barrier
// group; round-robin LDS service finishes everyone's reads together).
// Fix: frags are register-double-buffered one K-tile ahead:
//   - B(t+1) -> alternate set Bf0/Bf1 (read before the MFMA cluster)
//   - A(t+1)[mi] -> recycled in place: mi-major MFMA order kills Aq[mi]
//     after its 4 MFMAs; its ds_read re-load follows immediately.
// MFMA(t) therefore executes with ZERO lgkm waits; the 12 reads(t+1)
// complete under the ~1300cyc MFMA window. Critical pipe becomes MFMA
// (96 b128 reads = 1152cyc < 1306cyc MFMA per tile per CU).
// LDS: 4 buffers x (A 16KB + B 16KB) = 128KB; stage 4 ahead; VMCNT8
// retires S(t+2) at end of tile t; one barrier/tile publishes it.
// Regs: acc 128 AGPR + frags 64 VGPR (A 32 recycled + B 2x16) ~ 240
// combined -> 2 waves/SIMD (deliberate; overlap is intra-wave now).

__device__ __forceinline__ void load_lds16(const void* g, void* l) {
  __builtin_amdgcn_global_load_lds(
      (const __attribute__((address_space(1))) void*)g,
      (__attribute__((address_space(3))) void*)l,
      16, 0, 0);
}

// stage one 8KB unit (128 rows x 64 cols i8) of a [256][64] tile.
__device__ __forceinline__ void stage_unit(const i8* __restrict__ Gp, int K, int k0,
                                           i8* __restrict__ Tlds, int u, int wave,
                                           int lane) {
  const int base = u * 8192 + wave * 1024;        // physical byte base (wave-uniform)
  const int PA = base + lane * 16;                // this lane's physical bytes
  const int L = PA ^ (((PA >> 7) & 3) << 4);      // logical bytes (involution)
  const int r = L >> 6;                           // tile row (64 i8 per row)
  const int c = L & 63;                           // tile col (16-aligned)
  load_lds16(Gp + (size_t)r * K + k0 + c, Tlds + base);
}

#define BAR __builtin_amdgcn_s_barrier()
#define SGB __builtin_amdgcn_sched_barrier(0)
#define WAITL(N) asm volatile("s_waitcnt lgkmcnt(" #N ")" ::: "memory")
#define VMCNT8 asm volatile("s_waitcnt vmcnt(8)" ::: "memory")
#define VMCNT4 asm volatile("s_waitcnt vmcnt(4)" ::: "memory")
#define VMCNT0 asm volatile("s_waitcnt vmcnt(0)" ::: "memory")

// MFMA cluster, mi-major; after Aq[mi]'s last use, re-load it with tile
// t+1's fragment (register recycling keeps frag count at 64 regs).
#define CLUSTER_PRE(BCUR, PRA)                                                  \
  __builtin_amdgcn_s_setprio(1);                                                \
  _Pragma("unroll") for (int mi = 0; mi < 8; ++mi) {                            \
    _Pragma("unroll") for (int ni = 0; ni < 4; ++ni)                            \
      acc[mi][ni] = __builtin_amdgcn_mfma_i32_16x16x64_i8(                      \
          Aq[mi], BCUR[ni], acc[mi][ni], 0, 0, 0);                              \
    Aq[mi] = *(const i32x4*)((PRA) + abase + mi * 1024);                        \
    SGB;                                                                        \
  }                                                                             \
  __builtin_amdgcn_s_setprio(0);

#define CLUSTER_LAST(BCUR)                                                      \
  __builtin_amdgcn_s_setprio(1);                                                \
  _Pragma("unroll") for (int mi = 0; mi < 8; ++mi) {                            \
    _Pragma("unroll") for (int ni = 0; ni < 4; ++ni)                            \
      acc[mi][ni] = __builtin_amdgcn_mfma_i32_16x16x64_i8(                      \
          Aq[mi], BCUR[ni], acc[mi][ni], 0, 0, 0);                              \
  }                                                                             \
  __builtin_amdgcn_s_setprio(0);

// PSA/PSB: stage target buf[t&3] (epoch t+4). PRA/PRB: read source
// buf[(t+1)&3] (epoch t+1 frags). BCUR holds frags(t); BNXT <- frags(t+1).
// vmcnt: outstanding stages at tile end = epochs {t+2,t+3,t+4} < NT, 4
// loads each; retire S(t+2) so BAR publishes buf[(t+2)&3] for next tile's
// reads. Overwrite safety: staging epoch t+4 hits buf[t&3], whose reads
// (frags t) retired at tile t-1's WAITL(0) before BAR(t-1).
#define DO_TILE(t, PSA, PSB, PRA, PRB, BCUR, BNXT)                              \
  {                                                                             \
    if ((t) + 4 < NT) {                                                         \
      stage_unit(GA, K, ((t) + 4) * 64, PSA, 0, wave, lane);                    \
      stage_unit(GA, K, ((t) + 4) * 64, PSA, 1, wave, lane);                    \
      stage_unit(GB, K, ((t) + 4) * 64, PSB, 0, wave, lane);                    \
      stage_unit(GB, K, ((t) + 4) * 64, PSB, 1, wave, lane);                    \
    }                                                                           \
    if ((t) + 1 < NT) {                                                         \
      _Pragma("unroll") for (int ni = 0; ni < 4; ++ni)                          \
        BNXT[ni] = *(const i32x4*)((PRB) + bbase + ni * 1024);                  \
      SGB;                                                                      \
      CLUSTER_PRE(BCUR, PRA);                                                   \
    } else {                                                                    \
      SGB;                                                                      \
      CLUSTER_LAST(BCUR);                                                       \
    }                                                                           \
    WAITL(0);                                    /* reads(t+1) retired */       \
    if ((t) + 4 < NT) { VMCNT8; }                                               \
    else if ((t) + 3 < NT) { VMCNT4; }                                          \
    else if ((t) + 2 < NT) { VMCNT0; }                                          \
    BAR; SGB;                                                                   \
  }

__global__ __launch_bounds__(512, 2) void bingemm256_kernel(
    const i8* __restrict__ A,      // [M][K] i8 (x * 32)
    const i8* __restrict__ B,      // [N][K] i8 sign
    const float* __restrict__ alpha,
    const float* __restrict__ bias,
    float* __restrict__ C,         // [M][N] fp32
    int M, int N, int K) {
  __shared__ i8 AsmB[4][256 * 64];   // 4 x 16 KB
  __shared__ i8 BsmB[4][256 * 64];   // 4 x 16 KB  (128 KB total)

  const int tid = threadIdx.x;
  const int lane = tid & 63;
  const int wave = tid >> 6;  // 0..7
  const int wm = wave >> 2;   // 0..1
  const int wn = wave & 3;    // 0..3
  const int l15 = lane & 15;

  // XCD-aware swizzle (grid divisible by 8 -> simple bijection)
  const int nwg = gridDim.x;
  const int wg = blockIdx.x;
  const int wgid = ((nwg & 7) == 0) ? ((wg & 7) * (nwg >> 3) + (wg >> 3)) : wg;

  const int nbn = N / 256;
  const int tm = wgid / nbn;
  const int tn = wgid % nbn;

  const i8* GA = A + (size_t)tm * 256 * K;
  const i8* GB = B + (size_t)tn * 256 * K;

  // swizzled ds_read byte offsets (row stride 64B, granule 16B):
  // phys k-part = (kq ^ ((row>>1)&3))<<4, (row>>1)&3 == (l15>>1)&3
  const int kq = lane >> 4;                 // 0..3
  const int kph = ((kq ^ ((l15 >> 1) & 3)) << 4);
  const int abase = (wm * 128 + l15) * 64 + kph;   // + mi*1024 (16 rows)
  const int bbase = (wn * 64 + l15) * 64 + kph;    // + ni*1024

  i32x4 acc[8][4];
#pragma unroll
  for (int i = 0; i < 8; ++i)
#pragma unroll
    for (int j = 0; j < 4; ++j)
#pragma unroll
      for (int q = 0; q < 4; ++q) acc[i][j][q] = 0;

  const int NT = K / 64;

  i32x4 Aq[8], Bf0[4], Bf1[4];

  i8* const qA0 = &AsmB[0][0]; i8* const qA1 = &AsmB[1][0];
  i8* const qA2 = &AsmB[2][0]; i8* const qA3 = &AsmB[3][0];
  i8* const qB0 = &BsmB[0][0]; i8* const qB1 = &BsmB[1][0];
  i8* const qB2 = &BsmB[2][0]; i8* const qB3 = &BsmB[3][0];

  // ---- prologue: stage epochs 0..3; publish buf0,buf1; preload frags(0) --
  stage_unit(GA, K, 0, qA0, 0, wave, lane);
  stage_unit(GA, K, 0, qA0, 1, wave, lane);
  stage_unit(GB, K, 0, qB0, 0, wave, lane);
  stage_unit(GB, K, 0, qB0, 1, wave, lane);
  stage_unit(GA, K, 64, qA1, 0, wave, lane);
  stage_unit(GA, K, 64, qA1, 1, wave, lane);
  stage_unit(GB, K, 64, qB1, 0, wave, lane);
  stage_unit(GB, K, 64, qB1, 1, wave, lane);
  stage_unit(GA, K, 128, qA2, 0, wave, lane);
  stage_unit(GA, K, 128, qA2, 1, wave, lane);
  stage_unit(GB, K, 128, qB2, 0, wave, lane);
  stage_unit(GB, K, 128, qB2, 1, wave, lane);
  stage_unit(GA, K, 192, qA3, 0, wave, lane);
  stage_unit(GA, K, 192, qA3, 1, wave, lane);
  stage_unit(GB, K, 192, qB3, 0, wave, lane);
  stage_unit(GB, K, 192, qB3, 1, wave, lane);
  VMCNT8;   // retire epochs 0,1; keep 2,3 in flight
  BAR;
#pragma unroll
  for (int ni = 0; ni < 4; ++ni)
    Bf0[ni] = *(const i32x4*)(qB0 + bbase + ni * 1024);
#pragma unroll
  for (int mi = 0; mi < 8; ++mi)
    Aq[mi] = *(const i32x4*)(qA0 + abase + mi * 1024);
  WAITL(0); SGB;

  for (int t = 0; t < NT; t += 4) {
    DO_TILE(t,     qA0, qB0, qA1, qB1, Bf0, Bf1);
    DO_TILE(t + 1, qA1, qB1, qA2, qB2, Bf1, Bf0);
    DO_TILE(t + 2, qA2, qB2, qA3, qB3, Bf0, Bf1);
    DO_TILE(t + 3, qA3, qB3, qA0, qB0, Bf1, Bf0);
  }

  // ---- epilogue: C = acc * alpha[col]/32 + bias[col] (nontemporal) ----
  const int r0 = tm * 256 + wm * 128 + ((lane >> 4) << 2);
  const int c0 = tn * 256 + wn * 64 + l15;
#pragma unroll
  for (int an = 0; an < 4; ++an) {
    const int col = c0 + an * 16;
    const float al = alpha[col] * INV_XSCALE;
    const float bi = bias[col];
#pragma unroll
    for (int am = 0; am < 8; ++am) {
#pragma unroll
      for (int j = 0; j < 4; ++j) {
        __builtin_nontemporal_store((float)acc[am][an][j] * al + bi,
                                    &C[(size_t)(r0 + am * 16 + j) * N + col]);
      }
    }
  }
}

// ---------------- fallback (insurance: ws too small / bad dims) ----------------

__global__ __launch_bounds__(256) void naive_kernel(
    const float* __restrict__ x, const float* __restrict__ w,
    const float* __restrict__ alpha, const float* __restrict__ bias,
    float* __restrict__ out, int M, int N, int K) {
  long idx = (long)blockIdx.x * blockDim.x + threadIdx.x;
  const long total = (long)M * N;
  const long stride = (long)gridDim.x * blockDim.x;
  for (; idx < total; idx += stride) {
    const int m = (int)(idx / N);
    const int n = (int)(idx % N);
    const float* xr = x + (size_t)m * K;
    const float* wr = w + (size_t)n * K;
    float s = 0.0f;
    for (int k = 0; k < K; ++k) {
      const float wv = wr[k];
      const float sg = (wv > 0.0f) ? 1.0f : ((wv < 0.0f) ? -1.0f : 0.0f);
      s += xr[k] * sg;
    }
    out[idx] = s * alpha[n] + bias[n];
  }
}

// ---------------- launcher ----------------

extern "C" void kernel_launch(void* const* d_in, const int* in_sizes, int n_in,
                              void* d_out, int out_size, void* d_ws, size_t ws_size,
                              hipStream_t stream) {
  const float* x = (const float*)d_in[0];
  const float* w = (const float*)d_in[1];
  const float* alpha = (const float*)d_in[2];
  const float* bias = (const float*)d_in[3];
  float* out = (float*)d_out;

  const int OUT = in_sizes[3];                // bias length
  const int IN = in_sizes[1] / OUT;           // weight is [OUT][IN]
  const int M = in_sizes[0] / IN;             // x is [B][IN]
  const int N = OUT, K = IN;

  const size_t xbytes = (size_t)M * K;        // i8
  const size_t wbytes = (size_t)N * K;        // i8
  // NT = K/64 must be >= 4 and divisible by 4 (unroll-4 buffer rotation).
  const bool ok = (ws_size >= xbytes + wbytes) &&
                  (M % 256 == 0) && (N % 256 == 0) && (K % 256 == 0) &&
                  (K >= 256);

  if (!ok) {
    naive_kernel<<<2048, 256, 0, stream>>>(x, w, alpha, bias, out, M, N, K);
    return;
  }

  i8* xb = (i8*)d_ws;
  i8* wb = xb + xbytes;

  cvt_x_kernel<<<2048, 256, 0, stream>>>(x, (i32x4*)xb, (int)((size_t)M * K / 16));
  cvt_w_kernel<<<2048, 256, 0, stream>>>(w, (i32x4*)wb, (int)((size_t)N * K / 16));

  const int grid = (M / 256) * (N / 256);
  bingemm256_kernel<<<grid, 512, 0, stream>>>(xb, wb, alpha, bias, out, M, N, K);
}

// Round 4
// 246.869 us; speedup vs baseline: 4.4175x; 4.4175x over previous
//
#include <hip/hip_runtime.h>
#include <stdint.h>

typedef signed char i8;
typedef __attribute__((ext_vector_type(4))) float f32x4;
typedef __attribute__((ext_vector_type(4))) int i32x4;

#define XSCALE 32.0f
#define INV_XSCALE (1.0f / 32.0f)

// ---------------- conversion kernels ----------------

__device__ __forceinline__ int q8(float f) {
  float s = rintf(f * XSCALE);
  s = fminf(fmaxf(s, -127.0f), 127.0f);
  return ((int)s) & 0xff;
}

// x fp32 -> i8 (scale 32), 16 elems/thread
__global__ __launch_bounds__(256) void cvt_x_kernel(const float* __restrict__ x,
                                                    i32x4* __restrict__ o, int n16) {
  int i = blockIdx.x * blockDim.x + threadIdx.x;
  int stride = gridDim.x * blockDim.x;
  for (; i < n16; i += stride) {
    const f32x4* p = (const f32x4*)x + (size_t)i * 4;
    f32x4 v0 = p[0], v1 = p[1], v2 = p[2], v3 = p[3];
    i32x4 r;
    r[0] = q8(v0[0]) | (q8(v0[1]) << 8) | (q8(v0[2]) << 16) | (q8(v0[3]) << 24);
    r[1] = q8(v1[0]) | (q8(v1[1]) << 8) | (q8(v1[2]) << 16) | (q8(v1[3]) << 24);
    r[2] = q8(v2[0]) | (q8(v2[1]) << 8) | (q8(v2[2]) << 16) | (q8(v2[3]) << 24);
    r[3] = q8(v3[0]) | (q8(v3[1]) << 8) | (q8(v3[2]) << 16) | (q8(v3[3]) << 24);
    o[i] = r;
  }
}

__device__ __forceinline__ int sg8(float f) {
  return (f > 0.0f ? 1 : (f < 0.0f ? -1 : 0)) & 0xff;
}

// w fp32 -> sign i8 (+1/-1/0), 16 elems/thread
__global__ __launch_bounds__(256) void cvt_w_kernel(const float* __restrict__ w,
                                                    i32x4* __restrict__ o, int n16) {
  int i = blockIdx.x * blockDim.x + threadIdx.x;
  int stride = gridDim.x * blockDim.x;
  for (; i < n16; i += stride) {
    const f32x4* p = (const f32x4*)w + (size_t)i * 4;
    f32x4 v0 = p[0], v1 = p[1], v2 = p[2], v3 = p[3];
    i32x4 r;
    r[0] = sg8(v0[0]) | (sg8(v0[1]) << 8) | (sg8(v0[2]) << 16) | (sg8(v0[3]) << 24);
    r[1] = sg8(v1[0]) | (sg8(v1[1]) << 8) | (sg8(v1[2]) << 16) | (sg8(v1[3]) << 24);
    r[2] = sg8(v2[0]) | (sg8(v2[1]) << 8) | (sg8(v2[2]) << 16) | (sg8(v2[3]) << 24);
    r[3] = sg8(v3[0]) | (sg8(v3[1]) << 8) | (sg8(v3[2]) << 16) | (sg8(v3[3]) << 24);
    o[i] = r;
  }
}

// ---------------- 256x256 i8 MFMA GEMM, A-in-LDS / B-direct-global --------
// r17: cut LDS bytes instead of reordering them. r12-r15 were invariant at
// ~165us across schedule AND occupancy changes; the shared resource is the
// LDS port: 96 b128 frag-reads (A x4, B x2 amplification) + 32KB of staging
// writes ~ 1500-2000cyc/tile vs MFMA 1306cyc -> near-sum behavior. r16's
// register pipeline spilled (scratch traffic). This version removes B from
// LDS entirely: B fragments are 16 contiguous bytes in global ([N][K] i8,
// row col=n, bytes t*64+kq*16) and the whole B-panel is L2-resident, so
// each wave loads its 4 B-frags directly global->register, issued one tile
// ahead (a full ~2000cyc to cover ~300cyc L2 latency). LDS traffic drops
// 128KB->80KB per tile (A-read 64 + A-stage-write 16); MFMA becomes the
// critical pipe. Register classes identical to the clean r14 allocation
// (Alo/Ahi/Bb0/Bb1 16 x i32x4 + acc 128) -> no spill risk. LDS: 4 x 16KB
// A buffers, stage-2-ahead, one barrier + one VMCNT0 per tile (everything
// outstanding at the wait is >=1 tile old, so it drains for free).

__device__ __forceinline__ void load_lds16(const void* g, void* l) {
  __builtin_amdgcn_global_load_lds(
      (const __attribute__((address_space(1))) void*)g,
      (__attribute__((address_space(3))) void*)l,
      16, 0, 0);
}

// stage one 8KB unit (128 rows x 64 cols i8) of a [256][64] A-tile.
__device__ __forceinline__ void stage_unit(const i8* __restrict__ Gp, int K, int k0,
                                           i8* __restrict__ Tlds, int u, int wave,
                                           int lane) {
  const int base = u * 8192 + wave * 1024;        // physical byte base (wave-uniform)
  const int PA = base + lane * 16;                // this lane's physical bytes
  const int L = PA ^ (((PA >> 7) & 3) << 4);      // logical bytes (involution)
  const int r = L >> 6;                           // tile row (64 i8 per row)
  const int c = L & 63;                           // tile col (16-aligned)
  load_lds16(Gp + (size_t)r * K + k0 + c, Tlds + base);
}

#define BAR __builtin_amdgcn_s_barrier()
#define SGB __builtin_amdgcn_sched_barrier(0)
#define WAITL(N) asm volatile("s_waitcnt lgkmcnt(" #N ")" ::: "memory")
#define VMCNT0 asm volatile("s_waitcnt vmcnt(0)" ::: "memory")

#define READ_A_SET(PTR, DST, MI0)                                               \
  _Pragma("unroll") for (int mi = 0; mi < 4; ++mi)                              \
    DST[mi] = *(const i32x4*)((PTR) + abase + ((MI0) + mi) * 1024);

#define MFMA16(AS, BS, MB)                                                      \
  __builtin_amdgcn_s_setprio(1);                                                \
  _Pragma("unroll") for (int mi = 0; mi < 4; ++mi)                              \
  _Pragma("unroll") for (int ni = 0; ni < 4; ++ni)                              \
    acc[(MB) + mi][ni] = __builtin_amdgcn_mfma_i32_16x16x64_i8(                 \
        AS[mi], BS[ni], acc[(MB) + mi][ni], 0, 0, 0);                           \
  __builtin_amdgcn_s_setprio(0);

// PRC = bufA[t&3] (Ahi(t) source), PRN = bufA[(t+1)&3] (Alo(t+1) source),
// PSS = bufA[(t+2)&3] (stage target). BCUR = B(t) frags (loaded last tile),
// BNXT <- B(t+1) direct from global.
// lgkm invariant at tile entry: 4 outstanding (Alo(t), issued tile t-1).
#define DO_TILE(t, PRC, PRN, PSS, BCUR, BNXT)                                   \
  {                                                                             \
    READ_A_SET(PRC, Ahi, 4);                     /* [A] +4 lgkm (8 total) */    \
    if ((t) + 1 < NT) {                                                         \
      _Pragma("unroll") for (int ni = 0; ni < 4; ++ni)                          \
        BNXT[ni] = *(const i32x4*)(GBrow[ni] + (size_t)((t) + 1) * 64);         \
    }                                                                           \
    if ((t) + 2 < NT) {                                                         \
      stage_unit(GA, K, ((t) + 2) * 64, PSS, 0, wave, lane);                    \
      stage_unit(GA, K, ((t) + 2) * 64, PSS, 1, wave, lane);                    \
    }                                                                           \
    WAITL(4); SGB;                               /* Alo(t) ready */             \
    MFMA16(Alo, BCUR, 0);                        /* [C] */                      \
    SGB;                                                                        \
    if ((t) + 1 < NT) {                                                         \
      READ_A_SET(PRN, Alo, 0);                   /* [E] Alo(t+1), +4 lgkm */    \
      WAITL(4); SGB;                             /* retires Ahi(t) */           \
    } else { WAITL(0); SGB; }                                                   \
    MFMA16(Ahi, BCUR, 4);                        /* [G] */                      \
    SGB;                                                                        \
    VMCNT0;                                      /* B(t+1)+stage(t+2) landed */ \
    BAR;                                         /* publish stage(t+2) */       \
  }

__global__ __launch_bounds__(512, 2) void bingemm256_kernel(
    const i8* __restrict__ A,      // [M][K] i8 (x * 32)
    const i8* __restrict__ B,      // [N][K] i8 sign
    const float* __restrict__ alpha,
    const float* __restrict__ bias,
    float* __restrict__ C,         // [M][N] fp32
    int M, int N, int K) {
  __shared__ i8 AsmB[4][256 * 64];   // 4 x 16 KB = 64 KB (A only)

  const int tid = threadIdx.x;
  const int lane = tid & 63;
  const int wave = tid >> 6;  // 0..7
  const int wm = wave >> 2;   // 0..1
  const int wn = wave & 3;    // 0..3
  const int l15 = lane & 15;

  // XCD-aware swizzle (grid divisible by 8 -> simple bijection)
  const int nwg = gridDim.x;
  const int wg = blockIdx.x;
  const int wgid = ((nwg & 7) == 0) ? ((wg & 7) * (nwg >> 3) + (wg >> 3)) : wg;

  const int nbn = N / 256;
  const int tm = wgid / nbn;
  const int tn = wgid % nbn;

  const i8* GA = A + (size_t)tm * 256 * K;
  const i8* GB = B + (size_t)tn * 256 * K;

  // swizzled ds_read byte offsets for A (row stride 64B, granule 16B):
  // phys k-part = (kq ^ ((row>>1)&3))<<4, (row>>1)&3 == (l15>>1)&3
  const int kq = lane >> 4;                 // 0..3
  const int kph = ((kq ^ ((l15 >> 1) & 3)) << 4);
  const int abase = (wm * 128 + l15) * 64 + kph;   // + mi*1024 (16 rows)

  // B fragment global rows: frag ni = 16B at row (wn*64 + ni*16 + l15),
  // byte offset t*64 + kq*16 (identical logical bytes to the old LDS path).
  const i8* GBrow[4];
#pragma unroll
  for (int ni = 0; ni < 4; ++ni)
    GBrow[ni] = GB + (size_t)(wn * 64 + ni * 16 + l15) * K + kq * 16;

  i32x4 acc[8][4];
#pragma unroll
  for (int i = 0; i < 8; ++i)
#pragma unroll
    for (int j = 0; j < 4; ++j)
#pragma unroll
      for (int q = 0; q < 4; ++q) acc[i][j][q] = 0;

  const int NT = K / 64;

  i32x4 Alo[4], Ahi[4], Bb0[4], Bb1[4];

  i8* const qA0 = &AsmB[0][0]; i8* const qA1 = &AsmB[1][0];
  i8* const qA2 = &AsmB[2][0]; i8* const qA3 = &AsmB[3][0];

  // ---- prologue: stage A(0)->buf0, A(1)->buf1; B(0)->regs; preload Alo(0) --
  stage_unit(GA, K, 0, qA0, 0, wave, lane);
  stage_unit(GA, K, 0, qA0, 1, wave, lane);
  stage_unit(GA, K, 64, qA1, 0, wave, lane);
  stage_unit(GA, K, 64, qA1, 1, wave, lane);
#pragma unroll
  for (int ni = 0; ni < 4; ++ni)
    Bb0[ni] = *(const i32x4*)(GBrow[ni]);
  VMCNT0;
  BAR;
  READ_A_SET(qA0, Alo, 0);   // 4 lgkm outstanding -> loop invariant

  for (int t = 0; t < NT; t += 4) {
    DO_TILE(t,     qA0, qA1, qA2, Bb0, Bb1);
    DO_TILE(t + 1, qA1, qA2, qA3, Bb1, Bb0);
    DO_TILE(t + 2, qA2, qA3, qA0, Bb0, Bb1);
    DO_TILE(t + 3, qA3, qA0, qA1, Bb1, Bb0);
  }

  // ---- epilogue: C = acc * alpha[col]/32 + bias[col] (nontemporal) ----
  const int r0 = tm * 256 + wm * 128 + ((lane >> 4) << 2);
  const int c0 = tn * 256 + wn * 64 + l15;
#pragma unroll
  for (int an = 0; an < 4; ++an) {
    const int col = c0 + an * 16;
    const float al = alpha[col] * INV_XSCALE;
    const float bi = bias[col];
#pragma unroll
    for (int am = 0; am < 8; ++am) {
#pragma unroll
      for (int j = 0; j < 4; ++j) {
        __builtin_nontemporal_store((float)acc[am][an][j] * al + bi,
                                    &C[(size_t)(r0 + am * 16 + j) * N + col]);
      }
    }
  }
}

// ---------------- fallback (insurance: ws too small / bad dims) ----------------

__global__ __launch_bounds__(256) void naive_kernel(
    const float* __restrict__ x, const float* __restrict__ w,
    const float* __restrict__ alpha, const float* __restrict__ bias,
    float* __restrict__ out, int M, int N, int K) {
  long idx = (long)blockIdx.x * blockDim.x + threadIdx.x;
  const long total = (long)M * N;
  const long stride = (long)gridDim.x * blockDim.x;
  for (; idx < total; idx += stride) {
    const int m = (int)(idx / N);
    const int n = (int)(idx % N);
    const float* xr = x + (size_t)m * K;
    const float* wr = w + (size_t)n * K;
    float s = 0.0f;
    for (int k = 0; k < K; ++k) {
      const float wv = wr[k];
      const float sg = (wv > 0.0f) ? 1.0f : ((wv < 0.0f) ? -1.0f : 0.0f);
      s += xr[k] * sg;
    }
    out[idx] = s * alpha[n] + bias[n];
  }
}

// ---------------- launcher ----------------

extern "C" void kernel_launch(void* const* d_in, const int* in_sizes, int n_in,
                              void* d_out, int out_size, void* d_ws, size_t ws_size,
                              hipStream_t stream) {
  const float* x = (const float*)d_in[0];
  const float* w = (const float*)d_in[1];
  const float* alpha = (const float*)d_in[2];
  const float* bias = (const float*)d_in[3];
  float* out = (float*)d_out;

  const int OUT = in_sizes[3];                // bias length
  const int IN = in_sizes[1] / OUT;           // weight is [OUT][IN]
  const int M = in_sizes[0] / IN;             // x is [B][IN]
  const int N = OUT, K = IN;

  const size_t xbytes = (size_t)M * K;        // i8
  const size_t wbytes = (size_t)N * K;        // i8
  // NT = K/64 must be divisible by 4 (unroll-4 buffer indexing).
  const bool ok = (ws_size >= xbytes + wbytes) &&
                  (M % 256 == 0) && (N % 256 == 0) && (K % 256 == 0) &&
                  (K >= 256);

  if (!ok) {
    naive_kernel<<<2048, 256, 0, stream>>>(x, w, alpha, bias, out, M, N, K);
    return;
  }

  i8* xb = (i8*)d_ws;
  i8* wb = xb + xbytes;

  cvt_x_kernel<<<2048, 256, 0, stream>>>(x, (i32x4*)xb, (int)((size_t)M * K / 16));
  cvt_w_kernel<<<2048, 256, 0, stream>>>(w, (i32x4*)wb, (int)((size_t)N * K / 16));

  const int grid = (M / 256) * (N / 256);
  bingemm256_kernel<<<grid, 512, 0, stream>>>(xb, wb, alpha, bias, out, M, N, K);
}

// Round 5
// 173.600 us; speedup vs baseline: 6.2819x; 1.4221x over previous
//
#include <hip/hip_runtime.h>
#include <stdint.h>

typedef signed char i8;
typedef __attribute__((ext_vector_type(4))) float f32x4;
typedef __attribute__((ext_vector_type(4))) int i32x4;

#define XSCALE 32.0f
#define INV_XSCALE (1.0f / 32.0f)

// ---------------- conversion kernels ----------------

__device__ __forceinline__ int q8(float f) {
  float s = rintf(f * XSCALE);
  s = fminf(fmaxf(s, -127.0f), 127.0f);
  return ((int)s) & 0xff;
}

// x fp32 -> i8 (scale 32), 16 elems/thread
__global__ __launch_bounds__(256) void cvt_x_kernel(const float* __restrict__ x,
                                                    i32x4* __restrict__ o, int n16) {
  int i = blockIdx.x * blockDim.x + threadIdx.x;
  int stride = gridDim.x * blockDim.x;
  for (; i < n16; i += stride) {
    const f32x4* p = (const f32x4*)x + (size_t)i * 4;
    f32x4 v0 = p[0], v1 = p[1], v2 = p[2], v3 = p[3];
    i32x4 r;
    r[0] = q8(v0[0]) | (q8(v0[1]) << 8) | (q8(v0[2]) << 16) | (q8(v0[3]) << 24);
    r[1] = q8(v1[0]) | (q8(v1[1]) << 8) | (q8(v1[2]) << 16) | (q8(v1[3]) << 24);
    r[2] = q8(v2[0]) | (q8(v2[1]) << 8) | (q8(v2[2]) << 16) | (q8(v2[3]) << 24);
    r[3] = q8(v3[0]) | (q8(v3[1]) << 8) | (q8(v3[2]) << 16) | (q8(v3[3]) << 24);
    o[i] = r;
  }
}

__device__ __forceinline__ int sg8(float f) {
  return (f > 0.0f ? 1 : (f < 0.0f ? -1 : 0)) & 0xff;
}

// w fp32 -> sign i8 (+1/-1/0), 16 elems/thread
__global__ __launch_bounds__(256) void cvt_w_kernel(const float* __restrict__ w,
                                                    i32x4* __restrict__ o, int n16) {
  int i = blockIdx.x * blockDim.x + threadIdx.x;
  int stride = gridDim.x * blockDim.x;
  for (; i < n16; i += stride) {
    const f32x4* p = (const f32x4*)w + (size_t)i * 4;
    f32x4 v0 = p[0], v1 = p[1], v2 = p[2], v3 = p[3];
    i32x4 r;
    r[0] = sg8(v0[0]) | (sg8(v0[1]) << 8) | (sg8(v0[2]) << 16) | (sg8(v0[3]) << 24);
    r[1] = sg8(v1[0]) | (sg8(v1[1]) << 8) | (sg8(v1[2]) << 16) | (sg8(v1[3]) << 24);
    r[2] = sg8(v2[0]) | (sg8(v2[1]) << 8) | (sg8(v2[2]) << 16) | (sg8(v2[3]) << 24);
    r[3] = sg8(v3[0]) | (sg8(v3[1]) << 8) | (sg8(v3[2]) << 16) | (sg8(v3[3]) << 24);
    o[i] = r;
  }
}

// ---------------- 256x256 i8 MFMA GEMM -- m201 8-phase port ---------------
// r18: faithful port of the verified 256^2 8-phase schedule (m201, 62% of
// bf16 peak) to i8. r13/r14/r15 proved the 2-phase-per-K-tile structure
// plateaus at 42% regardless of barrier count / occupancy (the catalog's
// regime gate); r17 proved direct-global B is latency-poison. This is the
// proven template, adapted: BK=128 per iter, 4 phases (2 k-steps x 2
// mi-halves), per phase:
//   {4-8 ds_reads for THIS phase} {stage 2x8KB units of iter t+1}
//   [VMCNT4 at phases 1,3 only -- counted, never 0 in steady state]
//   BAR; lgkmcnt(0); setprio(1); 16 MFMA; setprio(0); BAR
// Reads issue pre-barrier, wait post-barrier: barrier convergence covers
// LDS latency. Stage slots p0:A(s0) p1:B(s0) p2:A(s1) p3:B(s1); VMCNT4 at
// p1 guarantees s1-units of iter t (staged slots p2,p3 of t-1, 4 newer
// instrs after), at p3 guarantees s0-units of t+1 (slots p0,p1 of t).
// Tail iters (no staging) tighten to VMCNT0. LDS 2 x 64KB dbuf = 128KB
// (1 block/CU). Registers: r13's clean classes (Af4+Bf4 frags + acc128).

__device__ __forceinline__ void load_lds16(const void* g, void* l) {
  __builtin_amdgcn_global_load_lds(
      (const __attribute__((address_space(1))) void*)g,
      (__attribute__((address_space(3))) void*)l,
      16, 0, 0);
}

// stage one 8KB unit (128 rows x 64 cols i8) of a [256][64] sub-tile.
__device__ __forceinline__ void stage_unit(const i8* __restrict__ Gp, int K, int k0,
                                           i8* __restrict__ Tlds, int u, int wave,
                                           int lane) {
  const int base = u * 8192 + wave * 1024;        // physical byte base (wave-uniform)
  const int PA = base + lane * 16;                // this lane's physical bytes
  const int L = PA ^ (((PA >> 7) & 3) << 4);      // logical bytes (involution)
  const int r = L >> 6;                           // tile row (64 i8 per row)
  const int c = L & 63;                           // tile col (16-aligned)
  load_lds16(Gp + (size_t)r * K + k0 + c, Tlds + base);
}

#define BAR __builtin_amdgcn_s_barrier()
#define SGB __builtin_amdgcn_sched_barrier(0)
#define WAITL0 asm volatile("s_waitcnt lgkmcnt(0)" ::: "memory")
#define VMCNT4 asm volatile("s_waitcnt vmcnt(4)" ::: "memory")
#define VMCNT0 asm volatile("s_waitcnt vmcnt(0)" ::: "memory")

// sub-tile byte offsets inside one 64KB buffer:
//   A(s) at s*16384, B(s) at 32768 + s*16384; each [256 rows][64 cols].
#define READ_A(CUR, S, MIH)                                                     \
  _Pragma("unroll") for (int mi = 0; mi < 4; ++mi)                              \
    Af[mi] = *(const i32x4*)((CUR) + (S) * 16384 + abase + ((MIH) * 4 + mi) * 1024);

#define READ_B(CUR, S)                                                          \
  _Pragma("unroll") for (int ni = 0; ni < 4; ++ni)                              \
    Bf[ni] = *(const i32x4*)((CUR) + 32768 + (S) * 16384 + bbase + ni * 1024);

#define CLUSTER(MIH)                                                            \
  __builtin_amdgcn_s_setprio(1);                                                \
  _Pragma("unroll") for (int mi = 0; mi < 4; ++mi)                              \
  _Pragma("unroll") for (int ni = 0; ni < 4; ++ni)                              \
    acc[(MIH) * 4 + mi][ni] = __builtin_amdgcn_mfma_i32_16x16x64_i8(            \
        Af[mi], Bf[ni], acc[(MIH) * 4 + mi][ni], 0, 0, 0);                      \
  __builtin_amdgcn_s_setprio(0);

// One iter = K-slab of 128 (2 k-steps), 4 phases. CUR read, NXT staged.
#define DO_ITER(t, CUR, NXT)                                                    \
  {                                                                             \
    const int k1 = ((t) + 1) * 128;                                             \
    const bool st = (t) + 1 < NTI;                                              \
    /* ---- p0: (s0, mi-lo) ---- */                                             \
    READ_A(CUR, 0, 0); READ_B(CUR, 0);                                          \
    if (st) { stage_unit(GA, K, k1, NXT, 0, wave, lane);                        \
              stage_unit(GA, K, k1, NXT, 1, wave, lane); }                      \
    BAR; WAITL0; SGB;                                                           \
    CLUSTER(0); SGB;                                                            \
    BAR;                                                                        \
    /* ---- p1: (s0, mi-hi) ---- */                                             \
    READ_A(CUR, 0, 1);                                                          \
    if (st) { stage_unit(GB, K, k1, NXT + 32768, 0, wave, lane);                \
              stage_unit(GB, K, k1, NXT + 32768, 1, wave, lane);                \
              VMCNT4; } else { VMCNT0; }                                        \
    BAR; WAITL0; SGB;                                                           \
    CLUSTER(1); SGB;                                                            \
    BAR;                                                                        \
    /* ---- p2: (s1, mi-lo) ---- */                                             \
    READ_A(CUR, 1, 0); READ_B(CUR, 1);                                          \
    if (st) { stage_unit(GA, K, k1 + 64, NXT + 16384, 0, wave, lane);           \
              stage_unit(GA, K, k1 + 64, NXT + 16384, 1, wave, lane); }         \
    BAR; WAITL0; SGB;                                                           \
    CLUSTER(0); SGB;                                                            \
    BAR;                                                                        \
    /* ---- p3: (s1, mi-hi) ---- */                                             \
    READ_A(CUR, 1, 1);                                                          \
    if (st) { stage_unit(GB, K, k1 + 64, NXT + 49152, 0, wave, lane);           \
              stage_unit(GB, K, k1 + 64, NXT + 49152, 1, wave, lane);           \
              VMCNT4; } else { VMCNT0; }                                        \
    BAR; WAITL0; SGB;                                                           \
    CLUSTER(1); SGB;                                                            \
    BAR;                                                                        \
  }

__global__ __launch_bounds__(512, 2) void bingemm256_kernel(
    const i8* __restrict__ A,      // [M][K] i8 (x * 32)
    const i8* __restrict__ B,      // [N][K] i8 sign
    const float* __restrict__ alpha,
    const float* __restrict__ bias,
    float* __restrict__ C,         // [M][N] fp32
    int M, int N, int K) {
  __shared__ i8 SM[2][65536];      // dbuf x {A s0, A s1, B s0, B s1} = 128 KB

  const int tid = threadIdx.x;
  const int lane = tid & 63;
  const int wave = tid >> 6;  // 0..7
  const int wm = wave >> 2;   // 0..1
  const int wn = wave & 3;    // 0..3
  const int l15 = lane & 15;

  // XCD-aware swizzle (grid divisible by 8 -> simple bijection)
  const int nwg = gridDim.x;
  const int wg = blockIdx.x;
  const int wgid = ((nwg & 7) == 0) ? ((wg & 7) * (nwg >> 3) + (wg >> 3)) : wg;

  const int nbn = N / 256;
  const int tm = wgid / nbn;
  const int tn = wgid % nbn;

  const i8* GA = A + (size_t)tm * 256 * K;
  const i8* GB = B + (size_t)tn * 256 * K;

  // swizzled ds_read byte offsets (row stride 64B, granule 16B):
  // phys k-part = (kq ^ ((row>>1)&3))<<4, (row>>1)&3 == (l15>>1)&3
  const int kq = lane >> 4;                 // 0..3
  const int kph = ((kq ^ ((l15 >> 1) & 3)) << 4);
  const int abase = (wm * 128 + l15) * 64 + kph;   // + (mih*4+mi)*1024
  const int bbase = (wn * 64 + l15) * 64 + kph;    // + ni*1024

  i32x4 acc[8][4];
#pragma unroll
  for (int i = 0; i < 8; ++i)
#pragma unroll
    for (int j = 0; j < 4; ++j)
#pragma unroll
      for (int q = 0; q < 4; ++q) acc[i][j][q] = 0;

  const int NTI = K / 128;

  i32x4 Af[4], Bf[4];

  i8* const SM0 = &SM[0][0];
  i8* const SM1 = &SM[1][0];

  // ---- prologue: stage iter 0 fully into buf0; retire its s0 half ----
  stage_unit(GA, K, 0,  SM0,         0, wave, lane);
  stage_unit(GA, K, 0,  SM0,         1, wave, lane);
  stage_unit(GB, K, 0,  SM0 + 32768, 0, wave, lane);
  stage_unit(GB, K, 0,  SM0 + 32768, 1, wave, lane);
  stage_unit(GA, K, 64, SM0 + 16384, 0, wave, lane);
  stage_unit(GA, K, 64, SM0 + 16384, 1, wave, lane);
  stage_unit(GB, K, 64, SM0 + 49152, 0, wave, lane);
  stage_unit(GB, K, 64, SM0 + 49152, 1, wave, lane);
  VMCNT4;   // s0 A+B landed; s1's 4 still in flight (covered by p1's VMCNT4)
  BAR;

  for (int t = 0; t < NTI; t += 2) {
    DO_ITER(t,     SM0, SM1);
    DO_ITER(t + 1, SM1, SM0);
  }

  // ---- epilogue: C = acc * alpha[col]/32 + bias[col] (nontemporal) ----
  const int r0 = tm * 256 + wm * 128 + ((lane >> 4) << 2);
  const int c0 = tn * 256 + wn * 64 + l15;
#pragma unroll
  for (int an = 0; an < 4; ++an) {
    const int col = c0 + an * 16;
    const float al = alpha[col] * INV_XSCALE;
    const float bi = bias[col];
#pragma unroll
    for (int am = 0; am < 8; ++am) {
#pragma unroll
      for (int j = 0; j < 4; ++j) {
        __builtin_nontemporal_store((float)acc[am][an][j] * al + bi,
                                    &C[(size_t)(r0 + am * 16 + j) * N + col]);
      }
    }
  }
}

// ---------------- fallback (insurance: ws too small / bad dims) ----------------

__global__ __launch_bounds__(256) void naive_kernel(
    const float* __restrict__ x, const float* __restrict__ w,
    const float* __restrict__ alpha, const float* __restrict__ bias,
    float* __restrict__ out, int M, int N, int K) {
  long idx = (long)blockIdx.x * blockDim.x + threadIdx.x;
  const long total = (long)M * N;
  const long stride = (long)gridDim.x * blockDim.x;
  for (; idx < total; idx += stride) {
    const int m = (int)(idx / N);
    const int n = (int)(idx % N);
    const float* xr = x + (size_t)m * K;
    const float* wr = w + (size_t)n * K;
    float s = 0.0f;
    for (int k = 0; k < K; ++k) {
      const float wv = wr[k];
      const float sg = (wv > 0.0f) ? 1.0f : ((wv < 0.0f) ? -1.0f : 0.0f);
      s += xr[k] * sg;
    }
    out[idx] = s * alpha[n] + bias[n];
  }
}

// ---------------- launcher ----------------

extern "C" void kernel_launch(void* const* d_in, const int* in_sizes, int n_in,
                              void* d_out, int out_size, void* d_ws, size_t ws_size,
                              hipStream_t stream) {
  const float* x = (const float*)d_in[0];
  const float* w = (const float*)d_in[1];
  const float* alpha = (const float*)d_in[2];
  const float* bias = (const float*)d_in[3];
  float* out = (float*)d_out;

  const int OUT = in_sizes[3];                // bias length
  const int IN = in_sizes[1] / OUT;           // weight is [OUT][IN]
  const int M = in_sizes[0] / IN;             // x is [B][IN]
  const int N = OUT, K = IN;

  const size_t xbytes = (size_t)M * K;        // i8
  const size_t wbytes = (size_t)N * K;        // i8
  // NTI = K/128 must be >= 2 and even (dbuf unroll-2) -> K % 256 == 0.
  const bool ok = (ws_size >= xbytes + wbytes) &&
                  (M % 256 == 0) && (N % 256 == 0) && (K % 256 == 0) &&
                  (K >= 256);

  if (!ok) {
    naive_kernel<<<2048, 256, 0, stream>>>(x, w, alpha, bias, out, M, N, K);
    return;
  }

  i8* xb = (i8*)d_ws;
  i8* wb = xb + xbytes;

  cvt_x_kernel<<<2048, 256, 0, stream>>>(x, (i32x4*)xb, (int)((size_t)M * K / 16));
  cvt_w_kernel<<<2048, 256, 0, stream>>>(w, (i32x4*)wb, (int)((size_t)N * K / 16));

  const int grid = (M / 256) * (N / 256);
  bingemm256_kernel<<<grid, 512, 0, stream>>>(xb, wb, alpha, bias, out, M, N, K);
}